// Round 5
// baseline (500.434 us; speedup 1.0000x reference)
//
#include <hip/hip_runtime.h>

#define TAGS 64
#define MAXT 512
#define NEG  -10000.0f
#define CH   8   // steps per chunk/phase

// Round-11 == round-10 resubmitted verbatim (bench infra died twice before
// launching; kernel audit found no barrier/bounds/ring hazard).
// Theory (fits rounds 0/1/3 exactly): per-WAVE issue cadence is ~4 cyc/instr
// (GCN 4-cycle SIMD rotation kept in CDNA4; wave64 op occupies SIMD-32 for
// only 2 cyc, so 1 wave/SIMD caps at ~25% of own issue BW). Per-step time ==
// ~4 x instrs on the serial wave: 293 instr -> 1330 cyc (r0), 340 -> 1409
// (r1), equal count -> equal time (r3). Fix = fewer instructions on the
// critical wave, not fewer hazards.
// Wave 0 (producer): round-0 LDS-broadcast value recurrence ONLY (~123
// instr/step -> ~520 cyc/step), publishes fv(t) AND m(t) to a 3-deep chunk
// ring. Waves 1-2 (consumers): trail one chunk; recompute c[p] = fv_prev[p]
// + w[lane][p] (bit-identical: same adds), read published m (exact), run the
// round-3-verified bitwise first-occurrence scan, write bptr. Quad-fused
// accumulation (no cv[64] array) keeps consumer VGPRs ~90 -> no spills
// (round 2's failure: VGPR_Count=84 meant the arrays spilled; here NO
// min-occupancy launch bound).
// Ring safety: phase c producer writes pub[c%3]; consumers read pub[(c-1)%3]
// (+ one slot of pub[(c-2)%3] written 2 phases ago). All disjoint; one
// __syncthreads per phase.
__global__ __launch_bounds__(192) void crf_viterbi(
    const float* __restrict__ feats,   // [B, T, K]
    const float* __restrict__ weights, // [K, K] (weights[next][prev])
    const int*   __restrict__ lens,    // [B]
    float*       __restrict__ out,     // [B] scores ++ [B*T] paths (as f32)
    int B, int T)
{
    const int b    = blockIdx.x;
    const int tid  = threadIdx.x;
    const int wv   = tid >> 6;                 // 0 = producer, 1..2 = consumers
    const int lane = tid & 63;                 // next tag
    const int len  = lens[b];                  // 1..T

    __shared__ float fbuf[2][CH * TAGS];       // 4 KB  feat staging (producer)
    __shared__ float pub[3][CH][2][TAGS];      // 12 KB ring: [..][0]=fv, [1]=m
    __shared__ unsigned char  bptr[MAXT * TAGS]; // 32 KB
    __shared__ unsigned short path[MAXT];        // 1 KB
    // ~50.2 KB LDS -> 3 blocks/CU (9 waves/CU, ~2-3 waves/SIMD)

#define F3(a, b, c) fmaxf(fmaxf((a), (b)), (c))
#define M3(a, b, c) min(min((a), (b)), (c))

    // W row for this lane (producer adds it; consumers re-add identically)
    float4 w4[16];
    #pragma unroll
    for (int i = 0; i < 16; ++i)
        w4[i] = *reinterpret_cast<const float4*>(weights + lane * TAGS + i * 4);
    const float wEnd = weights[1 * TAGS + lane];  // transition into END

    const float* fb  = feats + (size_t)b * T * TAGS;
    const int    lim = len * TAGS - 4;            // clamp for tail loads
    const int    nch = (len + CH - 1) / CH;

    float nf = NEG;                               // producer's running fv
    float4 n0 = {0,0,0,0}, n1 = {0,0,0,0};        // producer prefetch regs
    int cb = 0;

    if (wv == 0) {
        // seed fv(-1) into the slot phase-1 consumers read: pub[2][CH-1][0]
        pub[2][CH - 1][0][lane] = (lane == 0) ? 0.0f : NEG;
        // stage chunk 0 -> fbuf[0]; issue chunk-1 loads
        int o0 = 4 * lane;        if (o0 > lim) o0 = lim;
        int o1 = 256 + 4 * lane;  if (o1 > lim) o1 = lim;
        *reinterpret_cast<float4*>(&fbuf[0][4 * lane])       = *reinterpret_cast<const float4*>(fb + o0);
        *reinterpret_cast<float4*>(&fbuf[0][256 + 4 * lane]) = *reinterpret_cast<const float4*>(fb + o1);
        int p0 = CH * TAGS + 4 * lane;        if (p0 > lim) p0 = lim;
        int p1 = CH * TAGS + 256 + 4 * lane;  if (p1 > lim) p1 = lim;
        n0 = *reinterpret_cast<const float4*>(fb + p0);
        n1 = *reinterpret_cast<const float4*>(fb + p1);
    }
    __syncthreads();

    int m0 = 0;                                   // c % 3
    for (int c = 0; c <= nch; ++c) {
        const int m1 = (m0 == 0) ? 2 : m0 - 1;    // (c-1) % 3
        const int m2 = (m0 == 2) ? 0 : m0 + 1;    // (c+1) % 3 == (c-2) % 3

        if (wv == 0) {
            if (c < nch) {
                // ---- producer: value recurrence for chunk c ----
                const int n = min(CH, len - c * CH);
                float*       pw  = &pub[m0][0][0][0];
                const float* pr0 = &pub[m1][CH - 1][0][0];  // fv of step c*CH-1
                #pragma unroll
                for (int i = 0; i < CH; ++i) {
                    if (i < n) {
                        const float feat = fbuf[cb][i * TAGS + lane];
                        const float* fvp = (i == 0) ? pr0 : (pw + (i - 1) * 2 * TAGS);
                        float4 fq[16];
                        #pragma unroll
                        for (int g = 0; g < 16; ++g)
                            fq[g] = *reinterpret_cast<const float4*>(fvp + 4 * g);
                        float4 c4[16];
                        #pragma unroll
                        for (int g = 0; g < 16; ++g) {
                            c4[g].x = fq[g].x + w4[g].x;
                            c4[g].y = fq[g].y + w4[g].y;
                            c4[g].z = fq[g].z + w4[g].z;
                            c4[g].w = fq[g].w + w4[g].w;
                        }
                        const float* cc = reinterpret_cast<const float*>(c4);
                        // value-only max: 3-ary tree (v_max3_f32), depth 4
                        float v1[22];
                        #pragma unroll
                        for (int k = 0; k < 21; ++k) v1[k] = F3(cc[3*k], cc[3*k+1], cc[3*k+2]);
                        v1[21] = cc[63];
                        float v2[8];
                        #pragma unroll
                        for (int k = 0; k < 7; ++k) v2[k] = F3(v1[3*k], v1[3*k+1], v1[3*k+2]);
                        v2[7] = v1[21];
                        const float v30 = F3(v2[0], v2[1], v2[2]);
                        const float v31 = F3(v2[3], v2[4], v2[5]);
                        const float v32 = fmaxf(v2[6], v2[7]);
                        const float m   = F3(v30, v31, v32);

                        nf = m + feat;                       // emission after max
                        pw[i * 2 * TAGS + lane]        = nf; // publish fv(t)
                        pw[i * 2 * TAGS + TAGS + lane] = m;  // publish m(t)
                    }
                }
                // stage chunk c+1 (loads landed a chunk ago), issue chunk c+2
                *reinterpret_cast<float4*>(&fbuf[cb ^ 1][4 * lane])       = n0;
                *reinterpret_cast<float4*>(&fbuf[cb ^ 1][256 + 4 * lane]) = n1;
                int q0 = (c + 2) * CH * TAGS + 4 * lane;        if (q0 > lim) q0 = lim;
                int q1 = (c + 2) * CH * TAGS + 256 + 4 * lane;  if (q1 > lim) q1 = lim;
                n0 = *reinterpret_cast<const float4*>(fb + q0);
                n1 = *reinterpret_cast<const float4*>(fb + q1);
                cb ^= 1;
            }
        } else if (c > 0) {
            // ---- consumers: argmax + bptr for chunk c-1 ----
            const int ck = c - 1;
            const int n  = min(CH, len - ck * CH);
            const float* prd = &pub[m1][0][0][0];          // chunk (c-1)%3
            const float* pr0 = &pub[m2][CH - 1][0][0];     // fv of step ck*CH-1
            for (int i = wv - 1; i < n; i += 2) {
                const float* fvp = (i == 0) ? pr0 : (prd + (i - 1) * 2 * TAGS);
                const float  mm  = prd[i * 2 * TAGS + TAGS + lane];
                // bitwise first-occurrence scan (round-3-verified):
                // key = (bits(mm - c[p]) & ~63) | p ; winner's key == p.
                unsigned q[16];
                #pragma unroll
                for (int g = 0; g < 16; ++g) {
                    const float4 fq = *reinterpret_cast<const float4*>(fvp + 4 * g);
                    const float cx = fq.x + w4[g].x;
                    const float cy = fq.y + w4[g].y;
                    const float cz = fq.z + w4[g].z;
                    const float cw = fq.w + w4[g].w;
                    const unsigned k0 = (__float_as_uint(mm - cx) & 0xFFFFFFC0u) | (unsigned)(4*g+0);
                    const unsigned k1 = (__float_as_uint(mm - cy) & 0xFFFFFFC0u) | (unsigned)(4*g+1);
                    const unsigned k2 = (__float_as_uint(mm - cz) & 0xFFFFFFC0u) | (unsigned)(4*g+2);
                    const unsigned k3 = (__float_as_uint(mm - cw) & 0xFFFFFFC0u) | (unsigned)(4*g+3);
                    q[g] = min(M3(k0, k1, k2), k3);
                }
                const unsigned t0 = M3(q[0],  q[1],  q[2]);
                const unsigned t1 = M3(q[3],  q[4],  q[5]);
                const unsigned t2 = M3(q[6],  q[7],  q[8]);
                const unsigned t3 = M3(q[9],  q[10], q[11]);
                const unsigned t4 = M3(q[12], q[13], q[14]);
                const unsigned s0 = M3(t0, t1, t2);
                const unsigned s1 = M3(t3, t4, q[15]);
                const unsigned idx = min(s0, s1);          // == winner lane p
                bptr[(ck * CH + i) * TAGS + lane] = (unsigned char)idx;
            }
        }
        __syncthreads();
        m0 = m2;
    }

    if (wv != 0) return;   // consumers done (last barrier already passed)

    // terminal = fv + W[END][prev]; first-max argmax via shuffle butterfly
    float tv = nf + wEnd;
    int   ti = lane;
    #pragma unroll
    for (int off = 32; off >= 1; off >>= 1) {
        const float ov = __shfl_xor(tv, off);
        const int   oi = __shfl_xor(ti, off);
        if (ov > tv || (ov == tv && oi < ti)) { tv = ov; ti = oi; }
    }
    if (lane == 0) out[b] = tv;
    const int bestlast = ti;                      // uniform across lanes

    // padding region: path[t] = bestlast for t in [len-1, T)
    for (int t = lane; t < T; t += 64)
        if (t >= len - 1) path[t] = (unsigned short)bestlast;
    __builtin_amdgcn_wave_barrier();

    // serial chase (lane 0, LDS-resident backpointers)
    if (lane == 0) {
        int tag = bestlast;
        for (int t = len - 1; t >= 1; --t) {
            tag = bptr[t * TAGS + tag];
            path[t - 1] = (unsigned short)tag;
        }
    }
    __builtin_amdgcn_wave_barrier();

    // coalesced path writeback (tags as float32)
    float* pout = out + B + (size_t)b * T;
    for (int t = lane; t < T; t += 64)
        pout[t] = (float)path[t];
}

extern "C" void kernel_launch(void* const* d_in, const int* in_sizes, int n_in,
                              void* d_out, int out_size, void* d_ws, size_t ws_size,
                              hipStream_t stream) {
    const float* feats   = (const float*)d_in[0];
    const float* weights = (const float*)d_in[1];
    const int*   lens    = (const int*)d_in[2];
    float*       out     = (float*)d_out;

    const int B = in_sizes[2];
    const int T = in_sizes[0] / (B * TAGS);

    crf_viterbi<<<dim3(B), dim3(192), 0, stream>>>(feats, weights, lens, out, B, T);
}